// Round 4
// baseline (217.603 us; speedup 1.0000x reference)
//
#include <hip/hip_runtime.h>

#define BB 8
#define LL 2048
#define DD 256

typedef _Float16 half8 __attribute__((ext_vector_type(8)));
typedef float floatx4 __attribute__((ext_vector_type(4)));
typedef unsigned short ushort8 __attribute__((ext_vector_type(8)));

__device__ inline unsigned short f2h(float f) {
  _Float16 h = (_Float16)f;
  return __builtin_bit_cast(unsigned short, h);
}

// ---------------------------------------------------------------------------
// Kernel 0: W fp32 -> fp16, Wh[3][256][256].  grid 96, block 256.
// ---------------------------------------------------------------------------
__global__ __launch_bounds__(256) void wcvt(
    const float* __restrict__ Wq, const float* __restrict__ Wk,
    const float* __restrict__ Wv, unsigned short* __restrict__ Wh) {
  const int bm = blockIdx.x >> 5;
  const float* src = (bm == 0) ? Wq : (bm == 1) ? Wk : Wv;
  const int off = (blockIdx.x & 31) * 2048 + threadIdx.x * 8;
  float4 a = *(const float4*)(src + off);
  float4 b = *(const float4*)(src + off + 4);
  ushort8 u = {f2h(a.x), f2h(a.y), f2h(a.z), f2h(a.w),
               f2h(b.x), f2h(b.y), f2h(b.z), f2h(b.w)};
  *(ushort8*)(Wh + bm * 65536 + off) = u;
}

// ---------------------------------------------------------------------------
// Kernel 1: fused QKV projection (unchanged this round — diagnosing next).
// ---------------------------------------------------------------------------
__global__ __launch_bounds__(256) void proj(
    const float* __restrict__ x, const unsigned short* __restrict__ Wh,
    unsigned short* __restrict__ Qb, unsigned short* __restrict__ Kb,
    unsigned short* __restrict__ VT) {
  const int t = threadIdx.x;
  const int wave = t >> 6, lane = t & 63, quad = lane >> 4, m16 = lane & 15;
  const int l0g = blockIdx.x * 32;
  const int b = l0g >> 11, lb = l0g & 2047;

  half8 xf[2][8];
  for (int mt = 0; mt < 2; ++mt) {
    const float* xp = x + (size_t)(l0g + mt * 16 + m16) * DD + quad * 8;
    for (int kb = 0; kb < 8; ++kb) {
      float4 a = *(const float4*)(xp + kb * 32);
      float4 c = *(const float4*)(xp + kb * 32 + 4);
      ushort8 u = {f2h(a.x), f2h(a.y), f2h(a.z), f2h(a.w),
                   f2h(c.x), f2h(c.y), f2h(c.z), f2h(c.w)};
      xf[mt][kb] = __builtin_bit_cast(half8, u);
    }
  }

  for (int j = 0; j < 12; ++j) {
    const int nt = wave * 12 + j;
    const int mat = nt >> 4, ot = nt & 15;
    const unsigned short* wp =
        Wh + mat * 65536 + (ot * 16 + m16) * DD + quad * 8;
    floatx4 acc[2] = {{0, 0, 0, 0}, {0, 0, 0, 0}};
    if (mat < 2) {
      for (int kb = 0; kb < 8; ++kb) {
        half8 wf = __builtin_bit_cast(half8, *(const ushort8*)(wp + kb * 32));
        acc[0] = __builtin_amdgcn_mfma_f32_16x16x32_f16(xf[0][kb], wf, acc[0], 0, 0, 0);
        acc[1] = __builtin_amdgcn_mfma_f32_16x16x32_f16(xf[1][kb], wf, acc[1], 0, 0, 0);
      }
      unsigned short* Out = mat ? Kb : Qb;
      for (int mt = 0; mt < 2; ++mt)
        for (int r = 0; r < 4; ++r)
          Out[(size_t)(l0g + mt * 16 + quad * 4 + r) * DD + ot * 16 + m16] =
              f2h(acc[mt][r]);
    } else {
      for (int kb = 0; kb < 8; ++kb) {
        half8 wf = __builtin_bit_cast(half8, *(const ushort8*)(wp + kb * 32));
        acc[0] = __builtin_amdgcn_mfma_f32_16x16x32_f16(wf, xf[0][kb], acc[0], 0, 0, 0);
        acc[1] = __builtin_amdgcn_mfma_f32_16x16x32_f16(wf, xf[1][kb], acc[1], 0, 0, 0);
      }
      for (int mt = 0; mt < 2; ++mt)
        for (int r = 0; r < 4; ++r)
          VT[((size_t)(b * DD + ot * 16 + quad * 4 + r)) * LL + lb + mt * 16 +
             m16] = f2h(acc[mt][r]);
    }
  }
}

// ---------------------------------------------------------------------------
// Kernel 2: flash attention.  256 threads = 4 waves: qw = wave&1 (q-subtile),
// grp = wave>>1 (KV split).  q-tile 32, KV-tile 32/grp (64/iter).
// grid (64,8) = 512 blocks = 2 blocks/CU (LDS 69KB).  Register dbuf staging.
// ---------------------------------------------------------------------------
__global__ __launch_bounds__(256, 2) void attn(
    const unsigned short* __restrict__ Qb, const unsigned short* __restrict__ Kb,
    const unsigned short* __restrict__ VT, const int* __restrict__ lens,
    float* __restrict__ out) {
  // [0,32768): Ks 2 grp x 32x256   [32768,65536): Vs 2 grp x 256x32
  // [65536,70656): Ps 4 waves x 16x40
  __shared__ __attribute__((aligned(16))) unsigned char smem[70656];
  const int t = threadIdx.x;
  const int wave = t >> 6, lane = t & 63, quad = lane >> 4, m16 = lane & 15;
  const int qw = wave & 1, grp = wave >> 1;
  unsigned short* Ks = (unsigned short*)(smem + grp * 16384);
  unsigned short* Vs = (unsigned short*)(smem + 32768 + grp * 16384);
  unsigned short* Pw = (unsigned short*)(smem + 65536 + wave * 1280);

  const int b = blockIdx.y;
  const int q0 = blockIdx.x * 32;
  const int len = lens[b];
  const size_t baseQK = (size_t)b * LL * DD;
  const size_t baseVT = (size_t)b * DD * LL;

  half8 qf[8];
  {
    const unsigned short* qrow =
        Qb + baseQK + (size_t)(q0 + qw * 16 + m16) * DD + quad * 8;
    for (int kb = 0; kb < 8; ++kb)
      qf[kb] = __builtin_bit_cast(half8, *(const ushort8*)(qrow + kb * 32));
  }

  floatx4 O[16];
  for (int i = 0; i < 16; ++i) O[i] = (floatx4){0, 0, 0, 0};
  float mrow[4] = {-1e30f, -1e30f, -1e30f, -1e30f};
  float lrow[4] = {0.f, 0.f, 0.f, 0.f};

  ushort8 kreg[8], vreg[8];
  const unsigned short* kbase = Kb + baseQK;
  const unsigned short* vbase = VT + baseVT;

  // per-wave staging: wave (qw) stages half of its grp's K and V tiles
#define LOAD_TILES(KV0)                                                       \
  {                                                                           \
    for (int c = 0; c < 8; ++c) {                                             \
      int ch = qw * 512 + c * 64 + lane;                                      \
      kreg[c] = *(const ushort8*)(kbase + (size_t)((KV0) + (ch >> 5)) * DD +  \
                                  (ch & 31) * 8);                             \
      vreg[c] = *(const ushort8*)(vbase + (size_t)(ch >> 2) * LL + (KV0) +    \
                                  (ch & 3) * 8);                              \
    }                                                                         \
  }

  const int T = (len + 63) >> 6;  // 64 kv per iter (2 grps x 32)
  LOAD_TILES(grp * 32);

  for (int it = 0; it < T; ++it) {
    const int kv0 = it * 64 + grp * 32;
    __syncthreads();
    for (int c = 0; c < 8; ++c) {
      int ch = qw * 512 + c * 64 + lane;
      int row = ch >> 5, cc = ch & 31;
      *(ushort8*)&Ks[row * 256 + ((cc ^ (row & 7)) * 8)] = kreg[c];
      int d = ch >> 2, c2 = ch & 3;
      *(ushort8*)&Vs[d * 32 + c2 * 8] = vreg[c];
    }
    __syncthreads();
    if (it + 1 < T) LOAD_TILES(kv0 + 64);

    if (kv0 < len) {
      // S = Q K^T  (2 n-tiles x 8 k-steps)
      floatx4 s[2] = {{0, 0, 0, 0}, {0, 0, 0, 0}};
      for (int kb = 0; kb < 8; ++kb)
        for (int n = 0; n < 2; ++n) {
          half8 kf = __builtin_bit_cast(
              half8, *(const ushort8*)&Ks[(n * 16 + m16) * 256 +
                                          (((kb * 4 + quad) ^ (m16 & 7)) * 8)]);
          s[n] = __builtin_amdgcn_mfma_f32_16x16x32_f16(qf[kb], kf, s[n], 0, 0, 0);
        }
      float sv[2][4];
      for (int n = 0; n < 2; ++n) {
        bool valid = (kv0 + n * 16 + m16) < len;
        for (int r = 0; r < 4; ++r)
          sv[n][r] = valid ? s[n][r] * 0.0625f : -1e30f;
      }
      float al[4];
      for (int r = 0; r < 4; ++r) {
        float v = fmaxf(sv[0][r], sv[1][r]);
        v = fmaxf(v, __shfl_xor(v, 1));
        v = fmaxf(v, __shfl_xor(v, 2));
        v = fmaxf(v, __shfl_xor(v, 4));
        v = fmaxf(v, __shfl_xor(v, 8));
        float mn = fmaxf(mrow[r], v);
        al[r] = __expf(mrow[r] - mn);
        mrow[r] = mn;
        float sum = 0.f;
        for (int n = 0; n < 2; ++n) {
          float p = __expf(sv[n][r] - mn);
          Pw[(quad * 4 + r) * 40 + n * 16 + m16] = f2h(p);
          sum += p;
        }
        sum += __shfl_xor(sum, 1);
        sum += __shfl_xor(sum, 2);
        sum += __shfl_xor(sum, 4);
        sum += __shfl_xor(sum, 8);
        lrow[r] = lrow[r] * al[r] + sum;
      }
      // skip O-rescale when no lane's max moved (wave-uniform branch)
      if (__ballot(al[0] != 1.f || al[1] != 1.f || al[2] != 1.f ||
                   al[3] != 1.f)) {
        for (int i = 0; i < 16; ++i)
          for (int r = 0; r < 4; ++r) O[i][r] *= al[r];
      }
      half8 pf = __builtin_bit_cast(half8,
                                    *(const ushort8*)&Pw[m16 * 40 + quad * 8]);
      for (int nb = 0; nb < 16; ++nb) {
        half8 vf = __builtin_bit_cast(
            half8, *(const ushort8*)&Vs[(nb * 16 + m16) * 32 + quad * 8]);
        O[nb] = __builtin_amdgcn_mfma_f32_16x16x32_f16(pf, vf, O[nb], 0, 0, 0);
      }
    }
  }
#undef LOAD_TILES

  // ---- merge grp1 into grp0 via LDS (aliases Ks/Vs region) ----
  __syncthreads();
  float* Om = (float*)smem + qw * 4112;          // 16 rows x 257 f32
  float* ml = (float*)(smem + 33024) + qw * 32;  // [16][2]
  if (grp == 1) {
    for (int nb = 0; nb < 16; ++nb)
      for (int r = 0; r < 4; ++r)
        Om[(quad * 4 + r) * 257 + nb * 16 + m16] = O[nb][r];
    if (m16 == 0)
      for (int r = 0; r < 4; ++r) {
        ml[(quad * 4 + r) * 2] = mrow[r];
        ml[(quad * 4 + r) * 2 + 1] = lrow[r];
      }
  }
  __syncthreads();
  if (grp == 0) {
    float a[4], bf[4], inv[4];
    for (int r = 0; r < 4; ++r) {
      float mB = ml[(quad * 4 + r) * 2];
      float lB = ml[(quad * 4 + r) * 2 + 1];
      float m = fmaxf(mrow[r], mB);
      a[r] = __expf(mrow[r] - m);
      bf[r] = __expf(mB - m);
      inv[r] = 1.f / (lrow[r] * a[r] + lB * bf[r]);
    }
    for (int nb = 0; nb < 16; ++nb)
      for (int r = 0; r < 4; ++r) {
        float ob = Om[(quad * 4 + r) * 257 + nb * 16 + m16];
        out[baseQK + (size_t)(q0 + qw * 16 + quad * 4 + r) * DD + nb * 16 +
            m16] = (O[nb][r] * a[r] + ob * bf[r]) * inv[r];
      }
  }
}

extern "C" void kernel_launch(void* const* d_in, const int* in_sizes, int n_in,
                              void* d_out, int out_size, void* d_ws, size_t ws_size,
                              hipStream_t stream) {
  const float* x = (const float*)d_in[0];
  const float* Wq = (const float*)d_in[1];
  const float* Wk = (const float*)d_in[2];
  const float* Wv = (const float*)d_in[3];
  const int* lens = (const int*)d_in[4];
  unsigned short* Qb = (unsigned short*)d_ws;
  unsigned short* Kb = Qb + (size_t)BB * LL * DD;
  unsigned short* VT = Kb + (size_t)BB * LL * DD;
  unsigned short* Wh = VT + (size_t)BB * LL * DD;
  float* out = (float*)d_out;

  wcvt<<<96, 256, 0, stream>>>(Wq, Wk, Wv, Wh);
  proj<<<512, 256, 0, stream>>>(x, Wh, Qb, Kb, VT);
  attn<<<dim3(64, 8), 256, 0, stream>>>(Qb, Kb, VT, lens, out);
}